// Round 4
// baseline (340.404 us; speedup 1.0000x reference)
//
#include <hip/hip_runtime.h>

#define EPS   0.01f
#define ALPHA 0.1f
#define H     60

__device__ __forceinline__ float softplusf(float x) {
    // stable: max(x,0) + log1p(exp(-|x|))
    float e = __expf(-fabsf(x));
    return fmaxf(x, 0.f) + __logf(1.f + e);
}

__device__ __forceinline__ unsigned bf16_rne(float x) {
    unsigned u = __builtin_bit_cast(unsigned, x);
    return (u + 0x7FFFu + ((u >> 16) & 1u)) >> 16;   // round-nearest-even
}
__device__ __forceinline__ unsigned pack2bf(float a, float b) {
    return bf16_rne(a) | (bf16_rne(b) << 16);
}

// ---- setup: g0 scalar + W2^T into ws (tiny) ----
__global__ void setup_kernel(const float* __restrict__ W2, const float* __restrict__ b1,
                             const float* __restrict__ b2, const float* __restrict__ W3,
                             const float* __restrict__ b3, float* __restrict__ ws) {
    const int tid = threadIdx.x;
    for (int i = tid; i < H * H; i += 256) {
        int j = i / H, k = i % H;
        ws[16 + k * H + j] = W2[i];          // W2T[k][j] = W2[j][k]
    }
    if (tid == 0) {
        float h1[H];
        for (int k = 0; k < H; ++k) h1[k] = softplusf(b1[k]);
        float z3 = b3[0];
        for (int j = 0; j < H; ++j) {
            float acc = b2[j];
            for (int k = 0; k < H; ++k) acc = fmaf(W2[j * H + k], h1[k], acc);
            z3 = fmaf(W3[j], softplusf(acc), z3);
        }
        ws[0] = softplusf(z3);
    }
}

// ---- kernel A: forward. Live state: h1[60] only. Streams t_j (bf16 pairs) + g. ----
__global__ __launch_bounds__(256) void fwd_kernel(
    const float* __restrict__ X,   const float* __restrict__ W1,
    const float* __restrict__ b1,  const float* __restrict__ W2,
    const float* __restrict__ b2,  const float* __restrict__ W3,
    const float* __restrict__ b3,  const float* __restrict__ Wim2,
    const float* __restrict__ Wim3,
    unsigned* __restrict__ tp, float* __restrict__ gbuf, int B)
{
    const int row = blockIdx.x * 256 + threadIdx.x;
    if (row >= B) return;

    const float2 xv = ((const float2*)X)[row];
    const float x0 = xv.x, x1 = xv.y;

    float h1v[H];
#pragma unroll
    for (int k = 0; k < H; ++k)
        h1v[k] = softplusf(fmaf(W1[2 * k], x0, fmaf(W1[2 * k + 1], x1, b1[k])));

    float z3 = fmaf(Wim3[0], x0, fmaf(Wim3[1], x1, b3[0]));
    float tprev = 0.f;

    for (int j = 0; j < H; ++j) {
        const float* __restrict__ wrow = &W2[j * H];
        float a0 = 0.f, a1 = 0.f, a2 = 0.f, a3 = 0.f;
#pragma unroll
        for (int k = 0; k < H; k += 4) {
            a0 = fmaf(wrow[k + 0], h1v[k + 0], a0);
            a1 = fmaf(wrow[k + 1], h1v[k + 1], a1);
            a2 = fmaf(wrow[k + 2], h1v[k + 2], a2);
            a3 = fmaf(wrow[k + 3], h1v[k + 3], a3);
        }
        const float acc = ((a0 + a1) + (a2 + a3))
                        + fmaf(Wim2[2 * j], x0, fmaf(Wim2[2 * j + 1], x1, b2[j]));
        const float h2  = softplusf(acc);
        const float w3j = W3[j];
        z3 = fmaf(w3j, h2, z3);
        const float tj = w3j * (1.f - __expf(-h2));    // W3[j]*sigmoid(z2_j)
        if (j & 1) tp[(j >> 1) * B + row] = pack2bf(tprev, tj);
        else       tprev = tj;
    }
    gbuf[row] = softplusf(z3);
}

// ---- kernel B: backward + epilogue. Live state: t[60] only. ----
__global__ __launch_bounds__(256) void bwd_kernel(
    const float* __restrict__ X,    const float* __restrict__ Wf,
    const float* __restrict__ W1,   const float* __restrict__ b1,
    const float* __restrict__ W2T,  const float* __restrict__ Wim2,
    const float* __restrict__ Wim3, const float* __restrict__ g0p,
    const unsigned* __restrict__ tp, const float* __restrict__ gbuf,
    float* __restrict__ out, int B)
{
    const int row = blockIdx.x * 256 + threadIdx.x;
    if (row >= B) return;

    const float2 xv = ((const float2*)X)[row];
    const float x0 = xv.x, x1 = xv.y;

    float t[H];
    float gim0 = 0.f, gim1 = 0.f;     // sum_j t_j * Wim2[j,:]
#pragma unroll
    for (int p = 0; p < H / 2; ++p) {
        const unsigned u = tp[p * B + row];
        const float t0 = __builtin_bit_cast(float, u << 16);
        const float t1 = __builtin_bit_cast(float, u & 0xFFFF0000u);
        t[2 * p] = t0; t[2 * p + 1] = t1;
        gim0 = fmaf(t0, Wim2[4 * p + 0], fmaf(t1, Wim2[4 * p + 2], gim0));
        gim1 = fmaf(t0, Wim2[4 * p + 1], fmaf(t1, Wim2[4 * p + 3], gim1));
    }

    // q = sum_k (W2^T[k,:]·t) * sigmoid(z1_k) * W1[k,:]
    float q0 = 0.f, q1 = 0.f;
    for (int k = 0; k < H; ++k) {
        const float* __restrict__ wcol = &W2T[k * H];
        float a0 = 0.f, a1 = 0.f, a2 = 0.f, a3 = 0.f;
#pragma unroll
        for (int j = 0; j < H; j += 4) {
            a0 = fmaf(wcol[j + 0], t[j + 0], a0);
            a1 = fmaf(wcol[j + 1], t[j + 1], a1);
            a2 = fmaf(wcol[j + 2], t[j + 2], a2);
            a3 = fmaf(wcol[j + 3], t[j + 3], a3);
        }
        const float Gk  = (a0 + a1) + (a2 + a3);
        const float h1k = softplusf(fmaf(W1[2 * k], x0, fmaf(W1[2 * k + 1], x1, b1[k])));
        const float u1  = Gk * (1.f - __expf(-h1k));   // Gk * sigmoid(z1_k)
        q0 = fmaf(u1, W1[2 * k],     q0);
        q1 = fmaf(u1, W1[2 * k + 1], q1);
    }

    const float g0 = g0p[0];
    const float g  = gbuf[row];
    const float s3 = 1.f - __expf(-g);       // sigmoid(z3)
    const float u3 = (g > g0) ? s3 : 0.f;

    const float wi30 = Wim3[0], wi31 = Wim3[1];
    const float dV0 = fmaf(2.f * EPS, x0, u3 * (wi30 + gim0 + q0));
    const float dV1 = fmaf(2.f * EPS, x1, u3 * (wi31 + gim1 + q1));

    const float V  = fmaxf(g - g0, 0.f) + EPS * fmaf(x0, x0, x1 * x1);
    const float f0 = fmaf(Wf[0], x0, Wf[1] * x1);
    const float f1 = fmaf(Wf[2], x0, Wf[3] * x1);
    const float stab = fmaf(ALPHA, V, fmaf(dV0, f0, dV1 * f1));
    const float r    = fmaxf(stab, 0.f);
    const float n2   = fmaf(dV0, dV0, dV1 * dV1);
    const float s    = __fdividef(r, n2);

    float2 o;
    o.x = f0 - dV0 * s;
    o.y = f1 - dV1 * s;
    ((float2*)out)[row] = o;
}

// ---- fallback (round-2 monolithic) if ws is too small ----
__global__ void g0_kernel(const float* __restrict__ W2, const float* __restrict__ b1,
                          const float* __restrict__ b2, const float* __restrict__ W3,
                          const float* __restrict__ b3, float* __restrict__ g0_out) {
    if (threadIdx.x != 0 || blockIdx.x != 0) return;
    float h1[H];
    for (int k = 0; k < H; ++k) h1[k] = softplusf(b1[k]);
    float z3 = b3[0];
    for (int j = 0; j < H; ++j) {
        float acc = b2[j];
        for (int k = 0; k < H; ++k) acc = fmaf(W2[j * H + k], h1[k], acc);
        z3 = fmaf(W3[j], softplusf(acc), z3);
    }
    g0_out[0] = softplusf(z3);
}

__global__ __launch_bounds__(256) void sdnn_mono_kernel(
    const float* __restrict__ X,   const float* __restrict__ Wf,
    const float* __restrict__ W1,  const float* __restrict__ b1,
    const float* __restrict__ W2,  const float* __restrict__ b2,
    const float* __restrict__ W3,  const float* __restrict__ b3,
    const float* __restrict__ Wim2,const float* __restrict__ Wim3,
    const float* __restrict__ g0p, float* __restrict__ out, int B)
{
    const int row = blockIdx.x * 256 + threadIdx.x;
    if (row >= B) return;
    const float2 xv = ((const float2*)X)[row];
    const float x0 = xv.x, x1 = xv.y;
    float h1v[H];
#pragma unroll
    for (int k = 0; k < H; ++k)
        h1v[k] = softplusf(fmaf(W1[2 * k], x0, fmaf(W1[2 * k + 1], x1, b1[k])));
    float G[H];
#pragma unroll
    for (int k = 0; k < H; ++k) G[k] = 0.f;
    const float wi30 = Wim3[0], wi31 = Wim3[1];
    float z3 = fmaf(wi30, x0, fmaf(wi31, x1, b3[0]));
    float gim0 = 0.f, gim1 = 0.f;
    for (int j = 0; j < H; ++j) {
        const float* __restrict__ wrow = &W2[j * H];
        float a0 = 0.f, a1 = 0.f, a2 = 0.f, a3 = 0.f;
#pragma unroll
        for (int k = 0; k < H; k += 4) {
            a0 = fmaf(wrow[k + 0], h1v[k + 0], a0);
            a1 = fmaf(wrow[k + 1], h1v[k + 1], a1);
            a2 = fmaf(wrow[k + 2], h1v[k + 2], a2);
            a3 = fmaf(wrow[k + 3], h1v[k + 3], a3);
        }
        float acc = ((a0 + a1) + (a2 + a3))
                  + fmaf(Wim2[2 * j], x0, fmaf(Wim2[2 * j + 1], x1, b2[j]));
        const float h2  = softplusf(acc);
        const float w3j = W3[j];
        z3 = fmaf(w3j, h2, z3);
        const float tj = w3j * (1.f - __expf(-h2));
        gim0 = fmaf(tj, Wim2[2 * j],     gim0);
        gim1 = fmaf(tj, Wim2[2 * j + 1], gim1);
#pragma unroll
        for (int k = 0; k < H; ++k) G[k] = fmaf(wrow[k], tj, G[k]);
    }
    const float g0 = g0p[0];
    const float g  = softplusf(z3);
    const float s3 = 1.f - __expf(-g);
    const float u3 = (g > g0) ? s3 : 0.f;
    float q0 = 0.f, q1 = 0.f;
#pragma unroll
    for (int k = 0; k < H; ++k) {
        const float u1 = G[k] * (1.f - __expf(-h1v[k]));
        q0 = fmaf(u1, W1[2 * k],     q0);
        q1 = fmaf(u1, W1[2 * k + 1], q1);
    }
    const float dV0 = fmaf(2.f * EPS, x0, u3 * (wi30 + gim0 + q0));
    const float dV1 = fmaf(2.f * EPS, x1, u3 * (wi31 + gim1 + q1));
    const float V  = fmaxf(g - g0, 0.f) + EPS * fmaf(x0, x0, x1 * x1);
    const float f0 = fmaf(Wf[0], x0, Wf[1] * x1);
    const float f1 = fmaf(Wf[2], x0, Wf[3] * x1);
    const float stab = fmaf(ALPHA, V, fmaf(dV0, f0, dV1 * f1));
    const float r    = fmaxf(stab, 0.f);
    const float n2   = fmaf(dV0, dV0, dV1 * dV1);
    const float s    = __fdividef(r, n2);
    float2 o;
    o.x = f0 - dV0 * s;
    o.y = f1 - dV1 * s;
    ((float2*)out)[row] = o;
}

extern "C" void kernel_launch(void* const* d_in, const int* in_sizes, int n_in,
                              void* d_out, int out_size, void* d_ws, size_t ws_size,
                              hipStream_t stream) {
    const float* X    = (const float*)d_in[0];
    const float* Wf   = (const float*)d_in[1];
    const float* W1   = (const float*)d_in[2];
    const float* b1   = (const float*)d_in[3];
    const float* W2   = (const float*)d_in[4];
    const float* b2   = (const float*)d_in[5];
    const float* W3   = (const float*)d_in[6];
    const float* b3   = (const float*)d_in[7];
    const float* Wim2 = (const float*)d_in[8];
    const float* Wim3 = (const float*)d_in[9];
    float* out = (float*)d_out;

    const int B = in_sizes[0] / 2;
    const int nblk = (B + 255) / 256;

    float*    wsf  = (float*)d_ws;
    float*    g0p  = wsf;                         // ws[0]
    float*    W2T  = wsf + 16;                    // 3600 floats
    unsigned* tp   = (unsigned*)(wsf + 4096);     // 30*B u32 (bf16 pairs)
    float*    gbuf = (float*)(tp + (size_t)(H / 2) * B);  // B floats

    const size_t need = 4096ull * 4 + 4ull * (H / 2) * B + 4ull * B;

    if (ws_size >= need) {
        hipLaunchKernelGGL(setup_kernel, dim3(1), dim3(256), 0, stream,
                           W2, b1, b2, W3, b3, wsf);
        hipLaunchKernelGGL(fwd_kernel, dim3(nblk), dim3(256), 0, stream,
                           X, W1, b1, W2, b2, W3, b3, Wim2, Wim3, tp, gbuf, B);
        hipLaunchKernelGGL(bwd_kernel, dim3(nblk), dim3(256), 0, stream,
                           X, Wf, W1, b1, W2T, Wim2, Wim3, g0p, tp, gbuf, out, B);
    } else {
        hipLaunchKernelGGL(g0_kernel, dim3(1), dim3(64), 0, stream,
                           W2, b1, b2, W3, b3, wsf);
        hipLaunchKernelGGL(sdnn_mono_kernel, dim3(nblk), dim3(256), 0, stream,
                           X, Wf, W1, b1, W2, b2, W3, b3, Wim2, Wim3, wsf, out, B);
    }
}